// Round 9
// baseline (34.382 us; speedup 1.0000x reference)
//
#include <hip/hip_runtime.h>

#define H 32
#define C 64
#define K 15
#define SIGMA 0.3f
#define WAVES 4
#define QPW 4    // queries per wave

__global__ __launch_bounds__(256) void kpconv_kernel(
    const float* __restrict__ q_pts,
    const float* __restrict__ s_pts,
    const float* __restrict__ s_feats,
    const int*   __restrict__ inds,
    const float* __restrict__ weights,
    const float* __restrict__ kpts,
    float*       __restrict__ out,
    int N)
{
    // padded row (34 float2 = 272 B): q-rows stay 16B-aligned
    __shared__ float2 list[WAVES][QPW][34];   // 4.25 KB

    const int tid  = threadIdx.x;
    const int wave = tid >> 6;
    const int lane = tid & 63;
    const int half = lane >> 5;          // query within the pass
    const int hl   = lane & 31;          // neighbor slot

    // wave-uniform kernel points -> SGPRs via s_load
    float kp[K * 3];
    #pragma unroll
    for (int i = 0; i < K * 3; ++i) kp[i] = kpts[i];

    const int qBase = (blockIdx.x * WAVES + wave) * QPW;

    int c0 = 0, c1 = 0, c2 = 0, c3 = 0;  // active counts, wave-uniform

    // ---- Phase A: two passes, each pass = 2 queries x 32 neighbors ----
    #pragma unroll
    for (int p = 0; p < 2; ++p) {
        const int m = qBase + p * 2 + half;
        float infl = 0.0f;
        int   packed = 0;
        if (m < N) {
            const int idx = inds[m * H + hl];    // coalesced
            if (idx >= 0 && idx < N) {
                const float qx = q_pts[m * 3 + 0];
                const float qy = q_pts[m * 3 + 1];
                const float qz = q_pts[m * 3 + 2];
                const float nx = s_pts[idx * 3 + 0] - qx;
                const float ny = s_pts[idx * 3 + 1] - qy;
                const float nz = s_pts[idx * 3 + 2] - qz;
                float best = 1e30f;
                int   kbest = 0;
                #pragma unroll
                for (int k = 0; k < K; ++k) {    // math bit-identical to R6
                    const float dx = nx - kp[k * 3 + 0];
                    const float dy = ny - kp[k * 3 + 1];
                    const float dz = nz - kp[k * 3 + 2];
                    const float d2 = dx * dx + dy * dy + dz * dz;
                    if (d2 < best) { best = d2; kbest = k; }
                }
                infl = 1.0f - __builtin_amdgcn_sqrtf(best) * (1.0f / SIGMA);
                if (infl < 0.0f) infl = 0.0f;
                packed = idx | (kbest << 20);
            }
        }
        const unsigned long long ball = __ballot(infl > 0.0f);
        const unsigned int lo = (unsigned int)(ball & 0xFFFFFFFFu);
        const unsigned int hi = (unsigned int)(ball >> 32);
        const unsigned int maskH = half ? hi : lo;
        const int rank = __popc(maskH & ((1u << hl) - 1u));
        if (infl > 0.0f)
            list[wave][p * 2 + half][rank] = make_float2(__int_as_float(packed), infl);
        if (p == 0) { c0 = __popc(lo); c1 = __popc(hi); }
        else        { c2 = __popc(lo); c3 = __popc(hi); }
    }
    // same-wave LDS RAW: DS pipe is in-order per wave; no barrier needed.

    // ---- Phase B: quarter-wave per query, first 8 entries fully unrolled ----
    const int q  = lane >> 4;            // which of the 4 queries
    const int ql = lane & 15;            // channel group (4 channels)
    const int cq = (q < 2) ? (q == 0 ? c0 : c1) : (q == 2 ? c2 : c3);

    // read entries 0..7 (4x ds_read_b128, broadcast within quarter-wave)
    const float4* lrow = (const float4*)&list[wave][q][0];
    float4 e[4];
    e[0] = lrow[0]; e[1] = lrow[1]; e[2] = lrow[2]; e[3] = lrow[3];

    // predicated (idx,f) for j=0..7; j>=cq -> f=0, idx=0 (also guards
    // 0xAA-poisoned stale LDS entries from producing OOB gathers)
    int   pj[8];
    float fj[8];
    #pragma unroll
    for (int j = 0; j < 8; ++j) {
        const bool  v  = j < cq;
        const float pr = (j & 1) ? e[j >> 1].z : e[j >> 1].x;
        const float fr = (j & 1) ? e[j >> 1].w : e[j >> 1].y;
        pj[j] = v ? __float_as_int(pr) : 0;
        fj[j] = v ? fr : 0.0f;
    }

    // 16 independent gathers in flight, then FMA in rank order
    float4 a[8], w[8];
    #pragma unroll
    for (int j = 0; j < 8; ++j) {
        a[j] = *(const float4*)(s_feats + (size_t)(pj[j] & 0xFFFFF) * C + ql * 4);
        w[j] = *(const float4*)(weights + (pj[j] >> 20) * C + ql * 4);
    }
    float4 acc = make_float4(0.0f, 0.0f, 0.0f, 0.0f);
    #pragma unroll
    for (int j = 0; j < 8; ++j) {
        acc.x += a[j].x * w[j].x * fj[j];
        acc.y += a[j].y * w[j].y * fj[j];
        acc.z += a[j].z * w[j].z * fj[j];
        acc.w += a[j].w * w[j].w * fj[j];
    }

    // rare tail: cnt > 8, 2-at-a-time (same pattern as R6)
    for (int i = 8; i < cq; i += 2) {
        const float4 pf = *(const float4*)&list[wave][q][i];
        const int   p0   = __float_as_int(pf.x);
        const float f0   = pf.y;
        const bool  has1 = (i + 1) < cq;
        const int   p1   = has1 ? __float_as_int(pf.z) : 0;
        const float f1   = has1 ? pf.w : 0.0f;
        const float4 a0 = *(const float4*)(s_feats + (size_t)(p0 & 0xFFFFF) * C + ql * 4);
        const float4 w0 = *(const float4*)(weights + (p0 >> 20) * C + ql * 4);
        const float4 a1 = *(const float4*)(s_feats + (size_t)(p1 & 0xFFFFF) * C + ql * 4);
        const float4 w1 = *(const float4*)(weights + (p1 >> 20) * C + ql * 4);
        acc.x += a0.x * w0.x * f0;  acc.y += a0.y * w0.y * f0;
        acc.z += a0.z * w0.z * f0;  acc.w += a0.w * w0.w * f0;
        acc.x += a1.x * w1.x * f1;  acc.y += a1.y * w1.y * f1;
        acc.z += a1.z * w1.z * f1;  acc.w += a1.w * w1.w * f1;
    }

    const int mq = qBase + q;
    if (mq < N)
        *(float4*)(out + (size_t)mq * C + ql * 4) = acc;   // 256B per query
}

extern "C" void kernel_launch(void* const* d_in, const int* in_sizes, int n_in,
                              void* d_out, int out_size, void* d_ws, size_t ws_size,
                              hipStream_t stream) {
    const float* q_pts   = (const float*)d_in[0];
    const float* s_pts   = (const float*)d_in[1];
    const float* s_feats = (const float*)d_in[2];
    const int*   inds    = (const int*)d_in[3];
    const float* weights = (const float*)d_in[4];
    const float* kpts    = (const float*)d_in[5];
    float* out = (float*)d_out;

    const int N = in_sizes[0] / 3;               // q_pts is (N,3)
    const int qpb = WAVES * QPW;                 // 16 queries per block
    const int blocks = (N + qpb - 1) / qpb;      // 6250
    kpconv_kernel<<<blocks, 256, 0, stream>>>(q_pts, s_pts, s_feats, inds,
                                              weights, kpts, out, N);
}